// Round 4
// baseline (324.280 us; speedup 1.0000x reference)
//
#include <hip/hip_runtime.h>

typedef unsigned short u16;
typedef __attribute__((ext_vector_type(8))) short bf16x8;
typedef __attribute__((ext_vector_type(4))) float f32x4;
typedef __attribute__((ext_vector_type(2))) unsigned u32x2;
typedef __attribute__((ext_vector_type(4))) unsigned u32x4;

__device__ __forceinline__ u16 f2bf(float x) {
    union { float f; unsigned u; } v; v.f = x;
    unsigned r = v.u + 0x7FFF + ((v.u >> 16) & 1);
    return (u16)(r >> 16);
}

// pack 2 f32 -> 2 bf16 (RNE) in one op
__device__ __forceinline__ unsigned cvt_pk_bf16(float lo, float hi) {
    unsigned r;
    asm("v_cvt_pk_bf16_f32 %0, %1, %2" : "=v"(r) : "v"(lo), "v"(hi));
    return r;
}

// async global->LDS, 16B per lane; LDS dest = wave-uniform base + lane*16
__device__ __forceinline__ void gl_lds16(const u16* g, u16* l) {
    __builtin_amdgcn_global_load_lds((const __attribute__((address_space(1))) void*)g,
                                     (__attribute__((address_space(3))) void*)l, 16, 0, 0);
}

// ---------------------------------------------------------------------------
// fp32 -> bf16 flat convert, 8 elems/thread
// ---------------------------------------------------------------------------
__global__ __launch_bounds__(256) void conv_bf16(const float* __restrict__ in,
                                                 u16* __restrict__ out) {
    size_t i = ((size_t)blockIdx.x * 256 + threadIdx.x) * 8;
    const float4* p = (const float4*)(in + i);
    float4 a = p[0], b = p[1];
    u32x4 w = {cvt_pk_bf16(a.x, a.y), cvt_pk_bf16(a.z, a.w),
               cvt_pk_bf16(b.x, b.y), cvt_pk_bf16(b.z, b.w)};
    *(u32x4*)(out + i) = w;
}

// ---------------------------------------------------------------------------
// Transpose + convert: in fp32 [R][C] -> out bf16 [C][R]
// ---------------------------------------------------------------------------
__global__ __launch_bounds__(256) void transpose_w(const float* __restrict__ in,
                                                   u16* __restrict__ out, int R, int C) {
    __shared__ float tile[64][65];
    int r0 = blockIdx.y * 64, c0 = blockIdx.x * 64;
    int tid = threadIdx.x;
#pragma unroll
    for (int j = 0; j < 16; ++j) {
        int e = tid + j * 256;
        int row = e >> 6, col = e & 63;
        tile[row][col] = in[(size_t)(r0 + row) * C + c0 + col];
    }
    __syncthreads();
#pragma unroll
    for (int j = 0; j < 16; ++j) {
        int e = tid + j * 256;
        int row = e >> 6, col = e & 63;
        out[(size_t)(c0 + row) * R + r0 + col] = f2bf(tile[col][row]);
    }
}

// ---------------------------------------------------------------------------
// Transpose bf16 per (b,h): in [4096][64] -> out [64][4096]
// ---------------------------------------------------------------------------
__global__ __launch_bounds__(256) void transpose_v(const u16* __restrict__ in,
                                                   u16* __restrict__ out) {
    __shared__ u16 tile[64][65];
    int bh = blockIdx.y;
    int r0 = blockIdx.x * 64;
    const u16* ip = in + (size_t)bh * 4096 * 64;
    u16* op = out + (size_t)bh * 64 * 4096;
    int tid = threadIdx.x;
#pragma unroll
    for (int j = 0; j < 16; ++j) {
        int e = tid + j * 256;
        int row = e >> 6, col = e & 63;
        tile[row][col] = ip[(size_t)(r0 + row) * 64 + col];
    }
    __syncthreads();
#pragma unroll
    for (int j = 0; j < 16; ++j) {
        int e = tid + j * 256;
        int row = e >> 6, col = e & 63;
        op[(size_t)row * 4096 + r0 + col] = tile[col][row];
    }
}

// ---------------------------------------------------------------------------
// GEMM (m97-structure): C[M,N] = A[M,K] @ Bt[N,K]^T + bias. A bf16.
// BK=64, global_load_lds dwordx4 staging into linear LDS [128][64].
// MODE 0: out bf16 *(0.125*log2e) remapped to Q[B,NH,Lq,HD]
// MODE 1: out bf16 split to K (cols<512) / Vtmp (cols>=512)
// MODE 2: out fp32 row-major + bias
// ---------------------------------------------------------------------------
template <int MODE>
__global__ __launch_bounds__(256) void gemm_kernel(const u16* __restrict__ A,
                                                   const u16* __restrict__ Bt,
                                                   const float* __restrict__ bias,
                                                   void* __restrict__ Cout,
                                                   void* __restrict__ Cout2,
                                                   int M, int N, int K) {
    __shared__ u16 Al[128][64];
    __shared__ u16 Bl[128][64];
    int tid = threadIdx.x;
    int lane = tid & 63, wid = tid >> 6;
    int wr = wid >> 1, wc = wid & 1;
    int l15 = lane & 15, g = lane >> 4;
    int bm = blockIdx.y, bn = blockIdx.x;
    int ldr = lane >> 3, ldc = (lane & 7) << 3;  // chunk-local row/col

    f32x4 acc[4][4];
#pragma unroll
    for (int m = 0; m < 4; ++m)
#pragma unroll
        for (int n = 0; n < 4; ++n)
#pragma unroll
            for (int j = 0; j < 4; ++j) acc[m][n][j] = 0.f;

    int nK = K >> 6;
    for (int kt = 0; kt < nK; ++kt) {
        __syncthreads();
#pragma unroll
        for (int i = 0; i < 4; ++i) {
            int c = wid * 4 + i;          // 1KB chunk id (wave-uniform)
            int row = c * 8 + ldr;
            gl_lds16(A + (size_t)(bm * 128 + row) * K + kt * 64 + ldc, &Al[0][0] + c * 512);
            gl_lds16(Bt + (size_t)(bn * 128 + row) * K + kt * 64 + ldc, &Bl[0][0] + c * 512);
        }
        __syncthreads();  // drains vmcnt(0): LDS tiles complete

#pragma unroll
        for (int kk = 0; kk < 2; ++kk) {
            bf16x8 af[4], bfr[4];
#pragma unroll
            for (int m = 0; m < 4; ++m)
                af[m] = *(const bf16x8*)&Al[wr * 64 + m * 16 + l15][kk * 32 + g * 8];
#pragma unroll
            for (int n = 0; n < 4; ++n)
                bfr[n] = *(const bf16x8*)&Bl[wc * 64 + n * 16 + l15][kk * 32 + g * 8];
#pragma unroll
            for (int m = 0; m < 4; ++m)
#pragma unroll
                for (int n = 0; n < 4; ++n)
                    acc[m][n] =
                        __builtin_amdgcn_mfma_f32_16x16x32_bf16(af[m], bfr[n], acc[m][n], 0, 0, 0);
        }
    }

#pragma unroll
    for (int m = 0; m < 4; ++m)
#pragma unroll
        for (int n = 0; n < 4; ++n)
#pragma unroll
            for (int j = 0; j < 4; ++j) {
                int row = bm * 128 + wr * 64 + m * 16 + g * 4 + j;
                int col = bn * 128 + wc * 64 + n * 16 + l15;
                float v = acc[m][n][j] + bias[col];
                if (MODE == 0) {
                    // fold softmax scale (1/8) and log2(e) into Q
                    int b = row >> 10, q = row & 1023, h = col >> 6, d = col & 63;
                    ((u16*)Cout)[(((size_t)((b * 8 + h) * 1024 + q)) << 6) + d] =
                        f2bf(v * 0.18033688011112042f);
                } else if (MODE == 1) {
                    int b = row >> 12, kv = row & 4095;
                    int d = col & 63;
                    if (col < 512) {
                        int h = col >> 6;
                        ((u16*)Cout)[(((size_t)((b * 8 + h) * 4096 + kv)) << 6) + d] = f2bf(v);
                    } else {
                        int h = (col - 512) >> 6;
                        ((u16*)Cout2)[(((size_t)((b * 8 + h) * 4096 + kv)) << 6) + d] = f2bf(v);
                    }
                } else {
                    ((float*)Cout)[(size_t)row * N + col] = v;
                }
            }
}

// ---------------------------------------------------------------------------
// Flash attention, swapped QK^T (S^T fragments: q on l15, kv on (g,reg)).
// Static-max softmax in log2 domain (Q pre-scaled by 0.125*log2e, pos by
// log2e). KV-split sp=8. Block: 4 waves, 128 q rows (32/wave, 2 m-tiles),
// kv tiles of 64. P -> per-wave LDS via ds_write_b64, back as A-frag via
// ds_read_b128 (same l15). l via ones-MFMA on redistributed P.
// ---------------------------------------------------------------------------
__global__ __launch_bounds__(256, 4) void attn_kernel(const u16* __restrict__ Qb,
                                                      const u16* __restrict__ Kb,
                                                      const u16* __restrict__ Vt,
                                                      const float* __restrict__ pos,
                                                      float* __restrict__ Opart,
                                                      float* __restrict__ Lp) {
    __shared__ u16 Klds[64][72];
    __shared__ u16 Vlds[64][72];
    __shared__ u16 Plds[4][16][72];  // per-wave, reused across m (DS in-order)

    int idx = blockIdx.x;
    int bh = idx & 31;  // idx%8 = h -> per-XCD K/V/pos locality
    int zz = idx >> 5;
    int qt = zz & 7, sp = zz >> 3;
    int b = bh >> 3, h = bh & 7;
    int q0 = qt * 128;
    int kvbase = sp * 512;
    int tid = threadIdx.x, lane = tid & 63, wid = tid >> 6;
    int l15 = lane & 15, g = lane >> 4;

    bf16x8 aq[2][2];
#pragma unroll
    for (int m = 0; m < 2; ++m) {
        const u16* qp =
            Qb + (((size_t)((b * 8 + h) * 1024 + q0 + wid * 32 + m * 16 + l15)) << 6) + g * 8;
        aq[m][0] = *(const bf16x8*)(qp);
        aq[m][1] = *(const bf16x8*)(qp + 32);
    }

    f32x4 o[2][4];
    f32x4 lacc[2];
#pragma unroll
    for (int m = 0; m < 2; ++m) {
#pragma unroll
        for (int j = 0; j < 4; ++j) lacc[m][j] = 0.f;
#pragma unroll
        for (int n = 0; n < 4; ++n)
#pragma unroll
            for (int j = 0; j < 4; ++j) o[m][n][j] = 0.f;
    }

    const size_t kbase = ((size_t)(b * 8 + h)) * 4096 * 64;
    // pos row = q (l15-carried), col = kv (contiguous per lane -> float4)
    const float* posp =
        pos + (size_t)h * 1024 * 4096 + (size_t)(q0 + wid * 32 + l15) * 4096 + kvbase;

    int srow = tid >> 3, sc8 = (tid & 7) << 3;

    // prologue: prefetch K/V tile 0 + pos tile 0
    bf16x8 kr[2], vr[2];
    f32x4 zr[2][4];
#pragma unroll
    for (int j = 0; j < 2; ++j) {
        int row = srow + j * 32;
        kr[j] = *(const bf16x8*)(Kb + kbase + (size_t)(kvbase + row) * 64 + sc8);
        vr[j] = *(const bf16x8*)(Vt + kbase + (size_t)row * 4096 + kvbase + sc8);
    }
#pragma unroll
    for (int m = 0; m < 2; ++m)
#pragma unroll
        for (int n = 0; n < 4; ++n) {
            zr[m][n] = *(const f32x4*)(posp + (size_t)m * 16 * 4096 + n * 16 + g * 4);
#pragma unroll
            for (int j = 0; j < 4; ++j) zr[m][n][j] *= 1.44269504f;
        }

    const short one_s = (short)0x3F80;
    bf16x8 ones = {one_s, one_s, one_s, one_s, one_s, one_s, one_s, one_s};

    for (int kt = 0; kt < 8; ++kt) {
        __syncthreads();
#pragma unroll
        for (int j = 0; j < 2; ++j) {
            int row = srow + j * 32;
            *(bf16x8*)&Klds[row][sc8] = kr[j];
            *(bf16x8*)&Vlds[row][sc8] = vr[j];
        }
        __syncthreads();

        int knext = (kt + 1) & 7;
#pragma unroll
        for (int j = 0; j < 2; ++j) {
            int row = srow + j * 32;
            kr[j] = *(const bf16x8*)(Kb + kbase + (size_t)(kvbase + knext * 64 + row) * 64 + sc8);
            vr[j] = *(const bf16x8*)(Vt + kbase + (size_t)row * 4096 + kvbase + knext * 64 + sc8);
        }

        // S^T = (K Q^T)*log2e-scaled + pos*log2e (pos prefetched as C operand)
        // lane (l15,g) reg r: S[kv = n*16+g*4+r][q = m*16+l15]
        f32x4 s[2][4];
        __builtin_amdgcn_s_setprio(1);
#pragma unroll
        for (int n = 0; n < 4; ++n) {
            bf16x8 kb0 = *(const bf16x8*)&Klds[n * 16 + l15][g * 8];
            bf16x8 kb1 = *(const bf16x8*)&Klds[n * 16 + l15][32 + g * 8];
#pragma unroll
            for (int m = 0; m < 2; ++m) {
                f32x4 t =
                    __builtin_amdgcn_mfma_f32_16x16x32_bf16(kb0, aq[m][0], zr[m][n], 0, 0, 0);
                s[m][n] = __builtin_amdgcn_mfma_f32_16x16x32_bf16(kb1, aq[m][1], t, 0, 0, 0);
            }
        }
        __builtin_amdgcn_s_setprio(0);

        // prefetch pos for next tile (zr dead after QK), scale by log2e
#pragma unroll
        for (int m = 0; m < 2; ++m)
#pragma unroll
            for (int n = 0; n < 4; ++n) {
                zr[m][n] = *(const f32x4*)(posp + (size_t)m * 16 * 4096 + knext * 64 + n * 16 +
                                           g * 4);
#pragma unroll
                for (int j = 0; j < 4; ++j) zr[m][n][j] *= 1.44269504f;
            }

        // p = exp2(s)  (s already in log2 units; clamp guards fp32)
#pragma unroll
        for (int m = 0; m < 2; ++m)
#pragma unroll
            for (int n = 0; n < 4; ++n)
#pragma unroll
                for (int j = 0; j < 4; ++j)
                    s[m][n][j] = __builtin_exp2f(fminf(s[m][n][j], 80.f));

        // P redistribution: write pairs (adjacent kv) as b64, read back b128.
        // Producer lane (l15,g): q=l15, kv=n*16+g*4+r. Consumer: q=l15, kv=g*8..
        bf16x8 pa[2][2];
#pragma unroll
        for (int m = 0; m < 2; ++m) {
#pragma unroll
            for (int n = 0; n < 4; ++n) {
                u32x2 w;
                w.x = cvt_pk_bf16(s[m][n][0], s[m][n][1]);
                w.y = cvt_pk_bf16(s[m][n][2], s[m][n][3]);
                *(u32x2*)&Plds[wid][l15][n * 16 + g * 4] = w;
            }
            asm volatile("" ::: "memory");
            pa[m][0] = *(const bf16x8*)&Plds[wid][l15][g * 8];
            pa[m][1] = *(const bf16x8*)&Plds[wid][l15][32 + g * 8];
            asm volatile("" ::: "memory");
        }

        __builtin_amdgcn_s_setprio(1);
#pragma unroll
        for (int n = 0; n < 4; ++n) {
            bf16x8 vb0 = *(const bf16x8*)&Vlds[n * 16 + l15][g * 8];
            bf16x8 vb1 = *(const bf16x8*)&Vlds[n * 16 + l15][32 + g * 8];
#pragma unroll
            for (int m = 0; m < 2; ++m) {
                o[m][n] = __builtin_amdgcn_mfma_f32_16x16x32_bf16(pa[m][0], vb0, o[m][n], 0, 0, 0);
                o[m][n] = __builtin_amdgcn_mfma_f32_16x16x32_bf16(pa[m][1], vb1, o[m][n], 0, 0, 0);
            }
        }
        // row-sum l via ones-MFMA on the same bf16 P
#pragma unroll
        for (int m = 0; m < 2; ++m) {
            lacc[m] = __builtin_amdgcn_mfma_f32_16x16x32_bf16(pa[m][0], ones, lacc[m], 0, 0, 0);
            lacc[m] = __builtin_amdgcn_mfma_f32_16x16x32_bf16(pa[m][1], ones, lacc[m], 0, 0, 0);
        }
        __builtin_amdgcn_s_setprio(0);
    }

    int obase = (sp * 32 + bh) * 1024;
#pragma unroll
    for (int m = 0; m < 2; ++m)
#pragma unroll
        for (int j = 0; j < 4; ++j) {
            int row = q0 + wid * 32 + m * 16 + g * 4 + j;
#pragma unroll
            for (int n = 0; n < 4; ++n)
                Opart[((size_t)(obase + row)) * 64 + n * 16 + l15] = o[m][n][j];
            if (l15 == 0) Lp[obase + row] = lacc[m][j];
        }
}

// ---------------------------------------------------------------------------
// Merge 8 KV-splits: out = (sum O_s) / (sum l_s); apply row mask. bf16 AO.
// ---------------------------------------------------------------------------
__global__ __launch_bounds__(256) void attn_combine(const float* __restrict__ Opart,
                                                    const float* __restrict__ Lp,
                                                    const int* __restrict__ mask,
                                                    u16* __restrict__ AO) {
    int tid = threadIdx.x;
    int d = tid & 63;
    int r = blockIdx.x * 4 + (tid >> 6);  // (bh,q) row, 0..32767
    int bh = r >> 10, q = r & 1023;
    int b = bh >> 3, h = bh & 7;

    float L = 0.f, val = 0.f;
#pragma unroll
    for (int s2 = 0; s2 < 8; ++s2) {
        size_t rr = (size_t)(s2 * 32 + bh) * 1024 + q;
        L += Lp[rr];
        val += Opart[rr * 64 + d];
    }
    float res = mask[b * 1024 + q] ? (val / L) : 0.f;
    AO[((size_t)(b * 1024 + q)) * 512 + h * 64 + d] = f2bf(res);
}

// ---------------------------------------------------------------------------
extern "C" void kernel_launch(void* const* d_in, const int* in_sizes, int n_in,
                              void* d_out, int out_size, void* d_ws, size_t ws_size,
                              hipStream_t stream) {
    const float* Xq = (const float*)d_in[0];
    const float* Xkv = (const float*)d_in[1];
    const int* mask = (const int*)d_in[2];
    const float* Wq = (const float*)d_in[3];
    const float* bq = (const float*)d_in[4];
    const float* Wkv = (const float*)d_in[5];
    const float* bkv = (const float*)d_in[6];
    const float* Wp = (const float*)d_in[7];
    const float* bp = (const float*)d_in[8];
    const float* pos = (const float*)d_in[9];
    float* out = (float*)d_out;

    char* ws = (char*)d_ws;
    u16* WqT = (u16*)(ws);                   // 0.5MB [512][512] bf16
    u16* WkvT = (u16*)(ws + 524288);         // 1MB   [1024][512]
    u16* WpT = (u16*)(ws + 1572864);         // 0.5MB
    u16* Qb = (u16*)(ws + 2097152);          // 4MB   [B,NH,Lq,HD]
    u16* Kb = (u16*)(ws + 6291456);          // 16MB  [B,NH,Lkv,HD]
    u16* Vt = (u16*)(ws + 23068672);         // 16MB  [B,NH,HD,Lkv]
    u16* AO = (u16*)(ws + 39845888);         // 4MB   [B*Lq,E]
    float* Opart = (float*)(ws + 44040192);  // 64MB  [8][32][1024][64] fp32
    // dead-before-attn buffers aliased inside the Opart region:
    u16* Xkvb = (u16*)(ws + 44040192);       // 16MB  bf16 Xkv (dead after gemm<1>)
    u16* Vtm = (u16*)(ws + 60817408);        // 16MB  (dead after transpose_v)
    u16* Xqb = (u16*)(ws + 77594624);        // 4MB   bf16 Xq (dead after gemm<0>)
    float* Lp = (float*)(ws + 111149056);    // 1MB   [8][32][1024]

    conv_bf16<<<dim3(1024), 256, 0, stream>>>(Xq, Xqb);
    conv_bf16<<<dim3(4096), 256, 0, stream>>>(Xkv, Xkvb);
    transpose_w<<<dim3(8, 8), 256, 0, stream>>>(Wq, WqT, 512, 512);
    transpose_w<<<dim3(16, 8), 256, 0, stream>>>(Wkv, WkvT, 512, 1024);
    transpose_w<<<dim3(8, 8), 256, 0, stream>>>(Wp, WpT, 512, 512);
    gemm_kernel<0><<<dim3(4, 32), 256, 0, stream>>>(Xqb, WqT, bq, Qb, nullptr, 4096, 512, 512);
    gemm_kernel<1><<<dim3(8, 128), 256, 0, stream>>>(Xkvb, WkvT, bkv, Kb, Vtm, 16384, 1024, 512);
    transpose_v<<<dim3(64, 32), 256, 0, stream>>>(Vtm, Vt);
    attn_kernel<<<dim3(2048), 256, 0, stream>>>(Qb, Kb, Vt, pos, Opart, Lp);
    attn_combine<<<dim3(8192), 256, 0, stream>>>(Opart, Lp, mask, AO);
    gemm_kernel<2><<<dim3(4, 32), 256, 0, stream>>>(AO, WpT, bp, out, nullptr, 4096, 512, 512);
}

// Round 5
// 191.910 us; speedup vs baseline: 1.6897x; 1.6897x over previous
//
#include <hip/hip_runtime.h>

typedef unsigned short u16;
typedef __attribute__((ext_vector_type(8))) short bf16x8;
typedef __attribute__((ext_vector_type(4))) float f32x4;
typedef __attribute__((ext_vector_type(2))) unsigned u32x2;
typedef __attribute__((ext_vector_type(4))) unsigned u32x4;

__device__ __forceinline__ u16 f2bf(float x) {
    union { float f; unsigned u; } v; v.f = x;
    unsigned r = v.u + 0x7FFF + ((v.u >> 16) & 1);
    return (u16)(r >> 16);
}

// pack 2 f32 -> 2 bf16 (RNE) in one op
__device__ __forceinline__ unsigned cvt_pk_bf16(float lo, float hi) {
    unsigned r;
    asm("v_cvt_pk_bf16_f32 %0, %1, %2" : "=v"(r) : "v"(lo), "v"(hi));
    return r;
}

// async global->LDS, 16B per lane; LDS dest = wave-uniform base + lane*16
__device__ __forceinline__ void gl_lds16(const u16* g, u16* l) {
    __builtin_amdgcn_global_load_lds((const __attribute__((address_space(1))) void*)g,
                                     (__attribute__((address_space(3))) void*)l, 16, 0, 0);
}

// ---------------------------------------------------------------------------
// fp32 -> bf16 flat convert, 8 elems/thread
// ---------------------------------------------------------------------------
__global__ __launch_bounds__(256) void conv_bf16(const float* __restrict__ in,
                                                 u16* __restrict__ out) {
    size_t i = ((size_t)blockIdx.x * 256 + threadIdx.x) * 8;
    const float4* p = (const float4*)(in + i);
    float4 a = p[0], b = p[1];
    u32x4 w = {cvt_pk_bf16(a.x, a.y), cvt_pk_bf16(a.z, a.w),
               cvt_pk_bf16(b.x, b.y), cvt_pk_bf16(b.z, b.w)};
    *(u32x4*)(out + i) = w;
}

// ---------------------------------------------------------------------------
// Transpose + convert: in fp32 [R][C] -> out bf16 [C][R]
// ---------------------------------------------------------------------------
__global__ __launch_bounds__(256) void transpose_w(const float* __restrict__ in,
                                                   u16* __restrict__ out, int R, int C) {
    __shared__ float tile[64][65];
    int r0 = blockIdx.y * 64, c0 = blockIdx.x * 64;
    int tid = threadIdx.x;
#pragma unroll
    for (int j = 0; j < 16; ++j) {
        int e = tid + j * 256;
        int row = e >> 6, col = e & 63;
        tile[row][col] = in[(size_t)(r0 + row) * C + c0 + col];
    }
    __syncthreads();
#pragma unroll
    for (int j = 0; j < 16; ++j) {
        int e = tid + j * 256;
        int row = e >> 6, col = e & 63;
        out[(size_t)(c0 + row) * R + r0 + col] = f2bf(tile[col][row]);
    }
}

// ---------------------------------------------------------------------------
// Transpose bf16 per (b,h): in [4096][64] -> out [64][4096]
// ---------------------------------------------------------------------------
__global__ __launch_bounds__(256) void transpose_v(const u16* __restrict__ in,
                                                   u16* __restrict__ out) {
    __shared__ u16 tile[64][65];
    int bh = blockIdx.y;
    int r0 = blockIdx.x * 64;
    const u16* ip = in + (size_t)bh * 4096 * 64;
    u16* op = out + (size_t)bh * 64 * 4096;
    int tid = threadIdx.x;
#pragma unroll
    for (int j = 0; j < 16; ++j) {
        int e = tid + j * 256;
        int row = e >> 6, col = e & 63;
        tile[row][col] = ip[(size_t)(r0 + row) * 64 + col];
    }
    __syncthreads();
#pragma unroll
    for (int j = 0; j < 16; ++j) {
        int e = tid + j * 256;
        int row = e >> 6, col = e & 63;
        op[(size_t)row * 4096 + r0 + col] = tile[col][row];
    }
}

// ---------------------------------------------------------------------------
// GEMM (m97-structure): C[M,N] = A[M,K] @ Bt[N,K]^T + bias. A bf16.
// ---------------------------------------------------------------------------
template <int MODE>
__global__ __launch_bounds__(256) void gemm_kernel(const u16* __restrict__ A,
                                                   const u16* __restrict__ Bt,
                                                   const float* __restrict__ bias,
                                                   void* __restrict__ Cout,
                                                   void* __restrict__ Cout2,
                                                   int M, int N, int K) {
    __shared__ u16 Al[128][64];
    __shared__ u16 Bl[128][64];
    int tid = threadIdx.x;
    int lane = tid & 63, wid = tid >> 6;
    int wr = wid >> 1, wc = wid & 1;
    int l15 = lane & 15, g = lane >> 4;
    int bm = blockIdx.y, bn = blockIdx.x;
    int ldr = lane >> 3, ldc = (lane & 7) << 3;

    f32x4 acc[4][4];
#pragma unroll
    for (int m = 0; m < 4; ++m)
#pragma unroll
        for (int n = 0; n < 4; ++n)
#pragma unroll
            for (int j = 0; j < 4; ++j) acc[m][n][j] = 0.f;

    int nK = K >> 6;
    for (int kt = 0; kt < nK; ++kt) {
        __syncthreads();
#pragma unroll
        for (int i = 0; i < 4; ++i) {
            int c = wid * 4 + i;
            int row = c * 8 + ldr;
            gl_lds16(A + (size_t)(bm * 128 + row) * K + kt * 64 + ldc, &Al[0][0] + c * 512);
            gl_lds16(Bt + (size_t)(bn * 128 + row) * K + kt * 64 + ldc, &Bl[0][0] + c * 512);
        }
        __syncthreads();

#pragma unroll
        for (int kk = 0; kk < 2; ++kk) {
            bf16x8 af[4], bfr[4];
#pragma unroll
            for (int m = 0; m < 4; ++m)
                af[m] = *(const bf16x8*)&Al[wr * 64 + m * 16 + l15][kk * 32 + g * 8];
#pragma unroll
            for (int n = 0; n < 4; ++n)
                bfr[n] = *(const bf16x8*)&Bl[wc * 64 + n * 16 + l15][kk * 32 + g * 8];
#pragma unroll
            for (int m = 0; m < 4; ++m)
#pragma unroll
                for (int n = 0; n < 4; ++n)
                    acc[m][n] =
                        __builtin_amdgcn_mfma_f32_16x16x32_bf16(af[m], bfr[n], acc[m][n], 0, 0, 0);
        }
    }

#pragma unroll
    for (int m = 0; m < 4; ++m)
#pragma unroll
        for (int n = 0; n < 4; ++n)
#pragma unroll
            for (int j = 0; j < 4; ++j) {
                int row = bm * 128 + wr * 64 + m * 16 + g * 4 + j;
                int col = bn * 128 + wc * 64 + n * 16 + l15;
                float v = acc[m][n][j] + bias[col];
                if (MODE == 0) {
                    // fold softmax scale (1/8) and log2(e) into Q
                    int b = row >> 10, q = row & 1023, h = col >> 6, d = col & 63;
                    ((u16*)Cout)[(((size_t)((b * 8 + h) * 1024 + q)) << 6) + d] =
                        f2bf(v * 0.18033688011112042f);
                } else if (MODE == 1) {
                    int b = row >> 12, kv = row & 4095;
                    int d = col & 63;
                    if (col < 512) {
                        int h = col >> 6;
                        ((u16*)Cout)[(((size_t)((b * 8 + h) * 4096 + kv)) << 6) + d] = f2bf(v);
                    } else {
                        int h = (col - 512) >> 6;
                        ((u16*)Cout2)[(((size_t)((b * 8 + h) * 4096 + kv)) << 6) + d] = f2bf(v);
                    }
                } else {
                    ((float*)Cout)[(size_t)row * N + col] = v;
                }
            }
}

// ---------------------------------------------------------------------------
// Flash attention, 4-batch-fused. Block = (h, q-tile 64, sp kv-split of 4).
// pos tile loaded ONCE into regs (C operand), reused for all 4 b's.
// K/V for 4 b's staged via global_load_lds with XOR-swizzled source
// (byte ^= (row&7)<<4), read back with the same swizzle -> optimal b128
// bank utilization. Swapped QK^T (q on l15), exp2-direct, ones-MFMA l.
// Per wave: 16 q rows; wave wid stages batch b=wid.
// ---------------------------------------------------------------------------
__global__ __launch_bounds__(256, 2) void attn_kernel(const u16* __restrict__ Qb,
                                                      const u16* __restrict__ Kb,
                                                      const u16* __restrict__ Vt,
                                                      const float* __restrict__ pos,
                                                      float* __restrict__ Opart,
                                                      float* __restrict__ Lp) {
    __shared__ u16 Klds[4][4096];  // [b][swizzled 64x64], 8KB each
    __shared__ u16 Vlds[4][4096];
    __shared__ u16 Plds[4][16][72];  // per-wave P buffer

    int idx = blockIdx.x;
    int h = idx & 7;            // idx%8 = h -> per-XCD K/V/pos locality
    int rest = idx >> 3;
    int qt = rest & 15, sp = rest >> 4;
    int q0 = qt * 64;
    int kvbase = sp * 1024;
    int tid = threadIdx.x, lane = tid & 63, wid = tid >> 6;
    int l15 = lane & 15, g = lane >> 4;

    // Q fragments for all 4 batches (rows = q on l15)
    bf16x8 aq[4][2];
#pragma unroll
    for (int b = 0; b < 4; ++b) {
        const u16* qp =
            Qb + (((size_t)((b * 8 + h) * 1024 + q0 + wid * 16 + l15)) << 6) + g * 8;
        aq[b][0] = *(const bf16x8*)(qp);
        aq[b][1] = *(const bf16x8*)(qp + 32);
    }

    f32x4 o[4][4];
    f32x4 lacc[4];
#pragma unroll
    for (int b = 0; b < 4; ++b) {
#pragma unroll
        for (int j = 0; j < 4; ++j) lacc[b][j] = 0.f;
#pragma unroll
        for (int n = 0; n < 4; ++n)
#pragma unroll
            for (int j = 0; j < 4; ++j) o[b][n][j] = 0.f;
    }

    // staging: wave wid owns batch b=wid; inverse-swizzled global source
    const u16* Kg = Kb + ((size_t)(wid * 8 + h)) * 4096 * 64;
    const u16* Vg = Vt + ((size_t)(wid * 8 + h)) * 4096 * 64;
    u16* KldsW = &Klds[wid][0];
    u16* VldsW = &Vlds[wid][0];
    int lr = lane >> 3;                   // row-in-chunk 0..7
    int lcs = ((lane & 7) ^ lr) << 3;     // swizzled source col (u16 units)

    // pos row = q (l15), col = kv (contiguous -> f32x4)
    const float* posq =
        pos + (size_t)h * 1024 * 4096 + (size_t)(q0 + wid * 16 + l15) * 4096 + kvbase;

    const short one_s = (short)0x3F80;
    bf16x8 ones = {one_s, one_s, one_s, one_s, one_s, one_s, one_s, one_s};
    int sw = (l15 & 7) << 4;  // read-side swizzle (bytes)

    f32x4 zr[4];
    for (int kt = 0; kt < 16; ++kt) {
        int kv0 = kvbase + kt * 64;
        __syncthreads();  // all waves done reading prev tile's LDS
#pragma unroll
        for (int c = 0; c < 8; ++c)
            gl_lds16(Kg + (size_t)(kv0 + c * 8 + lr) * 64 + lcs, KldsW + c * 512);
#pragma unroll
        for (int c = 0; c < 8; ++c)
            gl_lds16(Vg + (size_t)(c * 8 + lr) * 4096 + kv0 + lcs, VldsW + c * 512);
        // pos tile for this kt (shared across all 4 b's), scaled to log2 units
#pragma unroll
        for (int n = 0; n < 4; ++n) {
            zr[n] = *(const f32x4*)(posq + kt * 64 + n * 16 + g * 4);
#pragma unroll
            for (int j = 0; j < 4; ++j) zr[n][j] *= 1.44269504f;
        }
        __syncthreads();  // drains vmcnt(0): K/V in LDS, zr loaded

#pragma unroll
        for (int b = 0; b < 4; ++b) {
            const char* KbL = (const char*)&Klds[b][0];
            const char* VbL = (const char*)&Vlds[b][0];

            // S^T = K_b . Q_b + pos   (rows kv = n*16+g*4+r, cols q = l15)
            f32x4 s[4];
            __builtin_amdgcn_s_setprio(1);
#pragma unroll
            for (int n = 0; n < 4; ++n) {
                bf16x8 kb0 = *(const bf16x8*)(KbL + (n * 16 + l15) * 128 + ((g * 16) ^ sw));
                bf16x8 kb1 = *(const bf16x8*)(KbL + (n * 16 + l15) * 128 + ((64 + g * 16) ^ sw));
                f32x4 t = __builtin_amdgcn_mfma_f32_16x16x32_bf16(kb0, aq[b][0], zr[n], 0, 0, 0);
                s[n] = __builtin_amdgcn_mfma_f32_16x16x32_bf16(kb1, aq[b][1], t, 0, 0, 0);
            }
            __builtin_amdgcn_s_setprio(0);

            // p = exp2(s) (s already log2-scaled; clamp guards fp32)
#pragma unroll
            for (int n = 0; n < 4; ++n)
#pragma unroll
                for (int j = 0; j < 4; ++j)
                    s[n][j] = __builtin_exp2f(fminf(s[n][j], 80.f));

            // P redistribution through per-wave LDS (b64 write, b128 read)
#pragma unroll
            for (int n = 0; n < 4; ++n) {
                u32x2 w;
                w.x = cvt_pk_bf16(s[n][0], s[n][1]);
                w.y = cvt_pk_bf16(s[n][2], s[n][3]);
                *(u32x2*)&Plds[wid][l15][n * 16 + g * 4] = w;
            }
            asm volatile("" ::: "memory");
            bf16x8 pa0 = *(const bf16x8*)&Plds[wid][l15][g * 8];
            bf16x8 pa1 = *(const bf16x8*)&Plds[wid][l15][32 + g * 8];
            asm volatile("" ::: "memory");

            __builtin_amdgcn_s_setprio(1);
#pragma unroll
            for (int n = 0; n < 4; ++n) {
                bf16x8 vb0 = *(const bf16x8*)(VbL + (n * 16 + l15) * 128 + ((g * 16) ^ sw));
                bf16x8 vb1 = *(const bf16x8*)(VbL + (n * 16 + l15) * 128 + ((64 + g * 16) ^ sw));
                o[b][n] = __builtin_amdgcn_mfma_f32_16x16x32_bf16(pa0, vb0, o[b][n], 0, 0, 0);
                o[b][n] = __builtin_amdgcn_mfma_f32_16x16x32_bf16(pa1, vb1, o[b][n], 0, 0, 0);
            }
            lacc[b] = __builtin_amdgcn_mfma_f32_16x16x32_bf16(pa0, ones, lacc[b], 0, 0, 0);
            lacc[b] = __builtin_amdgcn_mfma_f32_16x16x32_bf16(pa1, ones, lacc[b], 0, 0, 0);
            __builtin_amdgcn_s_setprio(0);
        }
    }

    // epilogue: fp32 partials + l
#pragma unroll
    for (int b = 0; b < 4; ++b) {
        int obase = (sp * 32 + b * 8 + h) * 1024;
#pragma unroll
        for (int j = 0; j < 4; ++j) {
            int row = q0 + wid * 16 + g * 4 + j;
#pragma unroll
            for (int n = 0; n < 4; ++n)
                Opart[((size_t)(obase + row)) * 64 + n * 16 + l15] = o[b][n][j];
            if (l15 == 0) Lp[obase + row] = lacc[b][j];
        }
    }
}

// ---------------------------------------------------------------------------
// Merge 4 KV-splits: out = (sum O_s) / (sum l_s); apply row mask. bf16 AO.
// ---------------------------------------------------------------------------
__global__ __launch_bounds__(256) void attn_combine(const float* __restrict__ Opart,
                                                    const float* __restrict__ Lp,
                                                    const int* __restrict__ mask,
                                                    u16* __restrict__ AO) {
    int tid = threadIdx.x;
    int d = tid & 63;
    int r = blockIdx.x * 4 + (tid >> 6);  // (bh,q) row, 0..32767
    int bh = r >> 10, q = r & 1023;
    int b = bh >> 3, h = bh & 7;

    float L = 0.f, val = 0.f;
#pragma unroll
    for (int s2 = 0; s2 < 4; ++s2) {
        size_t rr = (size_t)(s2 * 32 + bh) * 1024 + q;
        L += Lp[rr];
        val += Opart[rr * 64 + d];
    }
    float res = mask[b * 1024 + q] ? (val / L) : 0.f;
    AO[((size_t)(b * 1024 + q)) * 512 + h * 64 + d] = f2bf(res);
}

// ---------------------------------------------------------------------------
extern "C" void kernel_launch(void* const* d_in, const int* in_sizes, int n_in,
                              void* d_out, int out_size, void* d_ws, size_t ws_size,
                              hipStream_t stream) {
    const float* Xq = (const float*)d_in[0];
    const float* Xkv = (const float*)d_in[1];
    const int* mask = (const int*)d_in[2];
    const float* Wq = (const float*)d_in[3];
    const float* bq = (const float*)d_in[4];
    const float* Wkv = (const float*)d_in[5];
    const float* bkv = (const float*)d_in[6];
    const float* Wp = (const float*)d_in[7];
    const float* bp = (const float*)d_in[8];
    const float* pos = (const float*)d_in[9];
    float* out = (float*)d_out;

    char* ws = (char*)d_ws;
    u16* WqT = (u16*)(ws);                   // 0.5MB [512][512] bf16
    u16* WkvT = (u16*)(ws + 524288);         // 1MB   [1024][512]
    u16* WpT = (u16*)(ws + 1572864);         // 0.5MB
    u16* Qb = (u16*)(ws + 2097152);          // 4MB   [B,NH,Lq,HD]
    u16* Kb = (u16*)(ws + 6291456);          // 16MB  [B,NH,Lkv,HD]
    u16* Vt = (u16*)(ws + 23068672);         // 16MB  [B,NH,HD,Lkv]
    u16* AO = (u16*)(ws + 39845888);         // 4MB   [B*Lq,E]
    float* Opart = (float*)(ws + 44040192);  // 32MB  [4sp][32bh][1024][64] fp32
    // dead-before-attn buffers aliased inside the Opart region:
    u16* Xkvb = (u16*)(ws + 44040192);       // 16MB  bf16 Xkv (dead after gemm<1>)
    u16* Vtm = (u16*)(ws + 60817408);        // 16MB  (dead after transpose_v)
    u16* Xqb = (u16*)(ws + 77594624);        // 4MB   bf16 Xq (dead after gemm<0>)
    float* Lp = (float*)(ws + 111149056);    // 0.5MB [4sp][32bh][1024]

    conv_bf16<<<dim3(1024), 256, 0, stream>>>(Xq, Xqb);
    conv_bf16<<<dim3(4096), 256, 0, stream>>>(Xkv, Xkvb);
    transpose_w<<<dim3(8, 8), 256, 0, stream>>>(Wq, WqT, 512, 512);
    transpose_w<<<dim3(16, 8), 256, 0, stream>>>(Wkv, WkvT, 512, 1024);
    transpose_w<<<dim3(8, 8), 256, 0, stream>>>(Wp, WpT, 512, 512);
    gemm_kernel<0><<<dim3(4, 32), 256, 0, stream>>>(Xqb, WqT, bq, Qb, nullptr, 4096, 512, 512);
    gemm_kernel<1><<<dim3(8, 128), 256, 0, stream>>>(Xkvb, WkvT, bkv, Kb, Vtm, 16384, 1024, 512);
    transpose_v<<<dim3(64, 32), 256, 0, stream>>>(Vtm, Vt);
    attn_kernel<<<dim3(512), 256, 0, stream>>>(Qb, Kb, Vt, pos, Opart, Lp);
    attn_combine<<<dim3(8192), 256, 0, stream>>>(Opart, Lp, mask, AO);
    gemm_kernel<2><<<dim3(4, 32), 256, 0, stream>>>(AO, WpT, bp, out, nullptr, 4096, 512, 512);
}